// Round 8
// baseline (101.795 us; speedup 1.0000x reference)
//
#include <hip/hip_runtime.h>
#include <hip/hip_bf16.h>
#include <math.h>

#define BATCH 4096
#define NROW  8192
#define DIM   256

// zb holds bf16( sqrt(2*log2e) * z_hat ), so MFMA acc = 2*log2(e)*sim and
// exp(2*sim) == exp2(acc) — one v_exp_f32 per element, no mul.
#define SCALE_IN 1.69864360f              /* sqrt(2*1.4426950408889634) */
#define LN2      0.69314718055994531f     /* converts acc-units back to 2*sim */

typedef __attribute__((ext_vector_type(8))) short  short8;   // 8 bf16 / 4 VGPRs
typedef __attribute__((ext_vector_type(4))) float  floatx4;  // MFMA C/D

// ---------------------------------------------------------------------------
// ws layout:
//   zb     @ 0          : ushort[8192][256]  (4 MiB)  scaled-normalized bf16
//   part   @ 4 MiB      : float[8192]        row+col sums of exp (atomic)
//   bpart  @ 4 MiB+36864: float[2048]        per-block loss partials
// Fixed harness tax ~55-60 us/replay (256 MiB ws poison-fill ~43 us at
// ~6.2 TB/s inside the timed window + input restore + dispatch gaps).
// ---------------------------------------------------------------------------

// Wave-per-row: load fp32 row, L2-normalize, scale, write bf16. Also zeroes part.
__global__ __launch_bounds__(256) void k_prep(const float* __restrict__ z1,
                                              const float* __restrict__ z2,
                                              ushort* __restrict__ zb,
                                              float* __restrict__ part) {
  if (threadIdx.x < 4) part[blockIdx.x * 4 + threadIdx.x] = 0.f;

  int row  = blockIdx.x * 4 + (threadIdx.x >> 6);
  int lane = threadIdx.x & 63;
  const float4* src = (row < BATCH) ? (const float4*)(z1 + (size_t)row * DIM)
                                    : (const float4*)(z2 + (size_t)(row - BATCH) * DIM);
  float4 v = src[lane];
  float ss = v.x * v.x + v.y * v.y + v.z * v.z + v.w * v.w;
#pragma unroll
  for (int off = 1; off < 64; off <<= 1) ss += __shfl_xor(ss, off, 64);
  float s = SCALE_IN / fmaxf(sqrtf(ss), 1e-12f);
  __hip_bfloat16 h0 = __float2bfloat16(v.x * s), h1 = __float2bfloat16(v.y * s);
  __hip_bfloat16 h2 = __float2bfloat16(v.z * s), h3 = __float2bfloat16(v.w * s);
  ushort4 hb = {*(ushort*)&h0, *(ushort*)&h1, *(ushort*)&h2, *(ushort*)&h3};
  ((ushort4*)(zb + (size_t)row * DIM))[lane] = hb;
}

// ---------------------------------------------------------------------------
// Symmetric tile kernel with INTRA-WAVE SOFTWARE PIPELINE. 528 blocks (upper
// triangle of the 32x32 grid of 256x256 tiles), 256 threads / 4 waves, wave
// owns 64 rows (Af[4][8] = 128 VGPR pinned — legal here because (256,2)
// gives a 256-VGPR budget; R6's remat happened at a 128 budget).
// R2/R5/R7 post-mortems showed dur ~= SUM of MFMA+VALU+LDS pipe demands:
// the cs loop was a serial chain (ds_read -> MFMA -> exp) with reused regs.
// Fix: Bf double-buffer — next cs's 8 ds_read_b128 are issued between the
// current MFMA burst and the current exp burst, and accs are fresh per cs,
// so MFMA(cs+1)/loads(cs+1) are register-independent of exp(cs) and can
// overlap. Target: dur -> max(pipe demands) ~= 12-15 us instead of ~30.
// MFMA 16x16x32_bf16: A[m=lane&15][k=quad*8+j]; B[k][n=lane&15];
//                     C/D row=quad*4+reg, col=lane&15.
// ---------------------------------------------------------------------------
__global__ __launch_bounds__(256, 2) void k_simsum(const ushort* __restrict__ zb,
                                                   float* __restrict__ part) {
  __shared__ __align__(16) ushort Bt[64 * 264];   // 33792 B
  __shared__ float scol[4][256];                  // 4096 B

  // upper-triangle decode on the 32-grid: S(r) = r*(65-r)/2 blocks before row r
  int b = blockIdx.x;
  int r = (int)((65.0f - sqrtf(65.0f * 65.0f - 8.0f * (float)b)) * 0.5f);
  r = (r > 31) ? 31 : ((r < 0) ? 0 : r);
  while ((r + 1) * (65 - (r + 1)) / 2 <= b) r++;
  while (r * (65 - r) / 2 > b) r--;
  int c = r + (b - r * (65 - r) / 2);
  const bool diag = (r == c);

  const int tid  = threadIdx.x;
  const int w    = tid >> 6;
  const int lane = tid & 63;
  const int quad = lane >> 4;
  const int l16  = lane & 15;
  const int rowbase = r * 256 + w * 64;
  const int cbase   = c * 256;

  {
    float* sf = (float*)scol;
    sf[tid] = 0.f; sf[tid + 256] = 0.f; sf[tid + 512] = 0.f; sf[tid + 768] = 0.f;
  }

  // Pin A fragments: 4 rowblocks x 8 k-steps = 128 VGPRs
  short8 Af[4][8];
#pragma unroll
  for (int rb = 0; rb < 4; rb++) {
    const ushort* p = zb + (size_t)(rowbase + rb * 16 + l16) * DIM + quad * 8;
#pragma unroll
    for (int k = 0; k < 8; k++) Af[rb][k] = *(const short8*)(p + k * 32);
  }

  float rsum[4][4];
#pragma unroll
  for (int rb = 0; rb < 4; rb++)
#pragma unroll
    for (int rr = 0; rr < 4; rr++) rsum[rb][rr] = 0.f;

#pragma unroll 1
  for (int ct = 0; ct < 4; ct++) {
    const int c0 = cbase + ct * 64;
    __syncthreads();
    {
      const uint4* src = (const uint4*)(zb + (size_t)c0 * DIM);
#pragma unroll
      for (int i = 0; i < 8; i++) {
        int idx = tid + i * 256;
        int rr = idx >> 5, cc = idx & 31;
        *(uint4*)(&Bt[rr * 264 + cc * 8]) = src[rr * 32 + cc];
      }
    }
    __syncthreads();

    // Software-pipelined cs loop: Bf double-buffer, fresh accs per cs.
    short8 Bf[2][8];
    {
      const ushort* bp0 = &Bt[(0 * 16 + l16) * 264 + quad * 8];
#pragma unroll
      for (int k = 0; k < 8; k++) Bf[0][k] = *(const short8*)(bp0 + k * 32);
    }
#pragma unroll
    for (int cs = 0; cs < 4; cs++) {
      const int cur = cs & 1;
      // MFMA burst for current cs (fresh acc regs — no WAR with prior exp)
      floatx4 acc[4];
#pragma unroll
      for (int rb = 0; rb < 4; rb++) acc[rb] = (floatx4){0.f, 0.f, 0.f, 0.f};
#pragma unroll
      for (int k = 0; k < 8; k++)
#pragma unroll
        for (int rb = 0; rb < 4; rb++)
          acc[rb] = __builtin_amdgcn_mfma_f32_16x16x32_bf16(Af[rb][k], Bf[cur][k], acc[rb], 0, 0, 0);

      // Prefetch next cs's B fragments into the other buffer — these
      // ds_reads are independent of the exp burst below and can overlap it.
      if (cs < 3) {
        const ushort* bpn = &Bt[((cs + 1) * 16 + l16) * 264 + quad * 8];
#pragma unroll
        for (int k = 0; k < 8; k++) Bf[cur ^ 1][k] = *(const short8*)(bpn + k * 32);
      }

      // exp / accumulate for current cs
      float ca = 0.f;
#pragma unroll
      for (int rb = 0; rb < 4; rb++)
#pragma unroll
        for (int rr = 0; rr < 4; rr++) {
          float e = __builtin_amdgcn_exp2f(acc[rb][rr]);
          rsum[rb][rr] += e;
          ca += e;
        }
      if (!diag) {
        ca += __shfl_xor(ca, 16, 64);
        ca += __shfl_xor(ca, 32, 64);
        if (quad == 0)
          scol[w][ct * 64 + cs * 16 + l16] += ca;   // 16 lanes, 16 banks
      }
    }
  }

  // Row sums: reduce over the 16 column-lanes, atomics from l16==0 lanes.
#pragma unroll
  for (int rb = 0; rb < 4; rb++)
#pragma unroll
    for (int rr = 0; rr < 4; rr++) {
      float v = rsum[rb][rr];
#pragma unroll
      for (int off = 1; off < 16; off <<= 1) v += __shfl_xor(v, off, 64);
      if (l16 == 0)
        atomicAdd(&part[rowbase + rb * 16 + quad * 4 + rr], v);
    }

  if (!diag) {
    __syncthreads();
    float v = scol[0][tid] + scol[1][tid] + scol[2][tid] + scol[3][tid];
    atomicAdd(&part[cbase + tid], v);   // 256 coalesced lane-atomics
  }
}

// ---------------------------------------------------------------------------
// Wave-per-row loss term. 2048 blocks x 256 threads (4 rows/block).
//   neg_j = part[j] - exp2(selfdot_acc_j)    (matches the matmul diagonal)
//   t_j   = log(neg_j) - dp_acc_j * ln2      (dp_acc = 2*log2e*sim_pair)
// ---------------------------------------------------------------------------
__global__ __launch_bounds__(256) void k_rowterm(const ushort* __restrict__ zb,
                                                 const float* __restrict__ part,
                                                 float* __restrict__ bpart) {
  int j    = blockIdx.x * 4 + (threadIdx.x >> 6);
  int lane = threadIdx.x & 63;
  int pj   = (j + BATCH) & (NROW - 1);
  ushort4 ua = ((const ushort4*)(zb + (size_t)j  * DIM))[lane];
  ushort4 ub = ((const ushort4*)(zb + (size_t)pj * DIM))[lane];
  uint t;
  float ax, ay, az, aw, bx, by, bz, bw;
  t = (uint)ua.x << 16; ax = *(float*)&t;  t = (uint)ua.y << 16; ay = *(float*)&t;
  t = (uint)ua.z << 16; az = *(float*)&t;  t = (uint)ua.w << 16; aw = *(float*)&t;
  t = (uint)ub.x << 16; bx = *(float*)&t;  t = (uint)ub.y << 16; by = *(float*)&t;
  t = (uint)ub.z << 16; bz = *(float*)&t;  t = (uint)ub.w << 16; bw = *(float*)&t;
  float dp = ax * bx + ay * by + az * bz + aw * bw;
  float sd = ax * ax + ay * ay + az * az + aw * aw;
#pragma unroll
  for (int off = 1; off < 64; off <<= 1) {
    dp += __shfl_xor(dp, off, 64);
    sd += __shfl_xor(sd, off, 64);
  }
  __shared__ float sred[4];
  if (lane == 0) {
    float neg = part[j] - __builtin_amdgcn_exp2f(sd);
    sred[threadIdx.x >> 6] = logf(neg) - dp * LN2;
  }
  __syncthreads();
  if (threadIdx.x == 0)
    bpart[blockIdx.x] = sred[0] + sred[1] + sred[2] + sred[3];
}

__global__ void k_final(const float* __restrict__ bpart, float* __restrict__ out) {
  int t = threadIdx.x;  // 256 threads
  float v = 0.f;
#pragma unroll
  for (int i = 0; i < 8; i++) v += bpart[t + i * 256];
  int lane = t & 63;
#pragma unroll
  for (int off = 1; off < 64; off <<= 1) v += __shfl_xor(v, off, 64);
  __shared__ float sred[4];
  if (lane == 0) sred[t >> 6] = v;
  __syncthreads();
  if (t == 0) out[0] = (sred[0] + sred[1] + sred[2] + sred[3]) / (float)NROW;
}

extern "C" void kernel_launch(void* const* d_in, const int* in_sizes, int n_in,
                              void* d_out, int out_size, void* d_ws, size_t ws_size,
                              hipStream_t stream) {
  const float* z1 = (const float*)d_in[0];
  const float* z2 = (const float*)d_in[1];
  float* out = (float*)d_out;

  char* ws = (char*)d_ws;
  ushort* zb    = (ushort*)ws;                                   // 4 MiB
  float*  part  = (float*)(ws + (size_t)4 * 1024 * 1024);        // 32 KiB
  float*  bpart = (float*)(ws + (size_t)4 * 1024 * 1024 + 36864);

  k_prep<<<NROW / 4, 256, 0, stream>>>(z1, z2, zb, part);
  k_simsum<<<528, 256, 0, stream>>>(zb, part);
  k_rowterm<<<NROW / 4, 256, 0, stream>>>(zb, part, bpart);
  k_final<<<1, 256, 0, stream>>>(bpart, out);
}

// Round 9
// 100.841 us; speedup vs baseline: 1.0095x; 1.0095x over previous
//
#include <hip/hip_runtime.h>
#include <hip/hip_bf16.h>
#include <math.h>

#define BATCH 4096
#define NROW  8192
#define DIM   256

// zb holds bf16( sqrt(2*log2e) * z_hat ), so MFMA acc = 2*log2(e)*sim and
// exp(2*sim) == exp2(acc) — one v_exp_f32 per element, no mul.
#define SCALE_IN 1.69864360f              /* sqrt(2*1.4426950408889634) */
#define LN2      0.69314718055994531f     /* converts acc-units back to 2*sim */

typedef __attribute__((ext_vector_type(8))) short  short8;   // 8 bf16 / 4 VGPRs
typedef __attribute__((ext_vector_type(4))) float  floatx4;  // MFMA C/D

// async global->LDS, 16 B per lane, dest = wave-uniform base + lane*16
#define GLOAD_LDS(g, l)                                                        \
  __builtin_amdgcn_global_load_lds(                                            \
      (const __attribute__((address_space(1))) unsigned int*)(g),              \
      (__attribute__((address_space(3))) unsigned int*)(l), 16, 0, 0)

// ---------------------------------------------------------------------------
// ws layout:
//   zb     @ 0          : ushort[8192][256]  (4 MiB)  scaled-normalized bf16
//   part   @ 4 MiB      : float[8192]        row+col sums of exp (atomic)
//   bpart  @ 4 MiB+36864: float[2048]        per-block loss partials
// Fixed harness tax ~55-60 us/replay (256 MiB ws poison-fill ~44 us inside
// the timed window + input restore + dispatch gaps) — not addressable.
// ---------------------------------------------------------------------------

// Wave-per-row: load fp32 row, L2-normalize, scale, write bf16. Also zeroes part.
__global__ __launch_bounds__(256) void k_prep(const float* __restrict__ z1,
                                              const float* __restrict__ z2,
                                              ushort* __restrict__ zb,
                                              float* __restrict__ part) {
  if (threadIdx.x < 4) part[blockIdx.x * 4 + threadIdx.x] = 0.f;

  int row  = blockIdx.x * 4 + (threadIdx.x >> 6);
  int lane = threadIdx.x & 63;
  const float4* src = (row < BATCH) ? (const float4*)(z1 + (size_t)row * DIM)
                                    : (const float4*)(z2 + (size_t)(row - BATCH) * DIM);
  float4 v = src[lane];
  float ss = v.x * v.x + v.y * v.y + v.z * v.z + v.w * v.w;
#pragma unroll
  for (int off = 1; off < 64; off <<= 1) ss += __shfl_xor(ss, off, 64);
  float s = SCALE_IN / fmaxf(sqrtf(ss), 1e-12f);
  __hip_bfloat16 h0 = __float2bfloat16(v.x * s), h1 = __float2bfloat16(v.y * s);
  __hip_bfloat16 h2 = __float2bfloat16(v.z * s), h3 = __float2bfloat16(v.w * s);
  ushort4 hb = {*(ushort*)&h0, *(ushort*)&h1, *(ushort*)&h2, *(ushort*)&h3};
  ((ushort4*)(zb + (size_t)row * DIM))[lane] = hb;
}

// ---------------------------------------------------------------------------
// Symmetric tile kernel, m97-STYLE ASYNC STAGING. 528 blocks (upper triangle
// of the 32x32 grid of 256x256 tiles), 256 threads / 4 waves, wave owns 64
// rows (Af[4][8] = 128 VGPR pinned, (256,2) budget — no remat/spill).
// Staging: __builtin_amdgcn_global_load_lds width=16 (the m93->m97 lever,
// 517->874 TF) — no VGPR round-trip, no ds_writes, no staging address VALU.
// LDS dest is wave-uniform+lane*16 so NO PADDING is possible; bank uniformity
// instead comes from an XOR swizzle: logical 16B-chunk c of row r lives at
// phys chunk c^(r&7). The global-side vaddr is per-lane free, so staging
// scatters accordingly; B-frag ds_read_b128 uses 2 computed bases + imm
// offsets. Both staging and reads hit 8 lanes/bank-group = b128 BW minimum.
// MFMA 16x16x32_bf16: A[m=lane&15][k=quad*8+j]; B[k][n=lane&15];
//                     C/D row=quad*4+reg, col=lane&15.
// ---------------------------------------------------------------------------
__global__ __launch_bounds__(256, 2) void k_simsum(const ushort* __restrict__ zb,
                                                   float* __restrict__ part) {
  __shared__ __align__(16) ushort Bt[64 * 256];   // 32 KiB, NO pad (swizzled)
  __shared__ float scol[4][256];                  // 4 KiB

  // upper-triangle decode on the 32-grid: S(r) = r*(65-r)/2 blocks before row r
  int b = blockIdx.x;
  int r = (int)((65.0f - sqrtf(65.0f * 65.0f - 8.0f * (float)b)) * 0.5f);
  r = (r > 31) ? 31 : ((r < 0) ? 0 : r);
  while ((r + 1) * (65 - (r + 1)) / 2 <= b) r++;
  while (r * (65 - r) / 2 > b) r--;
  int c = r + (b - r * (65 - r) / 2);
  const bool diag = (r == c);

  const int tid  = threadIdx.x;
  const int w    = tid >> 6;
  const int lane = tid & 63;
  const int quad = lane >> 4;
  const int l16  = lane & 15;
  const int e    = l16 & 7;              // read-side swizzle key
  const int rowbase = r * 256 + w * 64;
  const int cbase   = c * 256;

  {
    float* sf = (float*)scol;
    sf[tid] = 0.f; sf[tid + 256] = 0.f; sf[tid + 512] = 0.f; sf[tid + 768] = 0.f;
  }

  // Pin A fragments: 4 rowblocks x 8 k-steps = 128 VGPRs
  short8 Af[4][8];
#pragma unroll
  for (int rb = 0; rb < 4; rb++) {
    const ushort* p = zb + (size_t)(rowbase + rb * 16 + l16) * DIM + quad * 8;
#pragma unroll
    for (int k = 0; k < 8; k++) Af[rb][k] = *(const short8*)(p + k * 32);
  }

  float rsum[4][4];
#pragma unroll
  for (int rb = 0; rb < 4; rb++)
#pragma unroll
    for (int rr = 0; rr < 4; rr++) rsum[rb][rr] = 0.f;

  // staging lane decomposition (constant across ct)
  const int shalf = lane >> 5;           // 0..1: which of the 2 rows/instr
  const int schnk = lane & 31;           // phys 16B chunk within the row

#pragma unroll 1
  for (int ct = 0; ct < 4; ct++) {
    const int c0 = cbase + ct * 64;
    __syncthreads();
    // Wave w stages local rows [w*16, w*16+16): 8 instrs x 2 rows (1 KiB).
    // Lane -> row rl = r0 + (lane>>5), phys chunk schnk holds logical chunk
    // schnk^(rl&7) -> global vaddr scatters, LDS fills contiguously.
#pragma unroll
    for (int j = 0; j < 8; j++) {
      const int r0 = w * 16 + j * 2;
      const int rl = r0 + shalf;
      const int csw = (schnk ^ (rl & 7)) * 8;          // ushort col offset
      GLOAD_LDS(zb + (size_t)(c0 + rl) * DIM + csw, &Bt[r0 * 256]);
    }
    __syncthreads();   // drains vmcnt(0): staged data visible

#pragma unroll
    for (int cs = 0; cs < 4; cs++) {
      const ushort* rowp = &Bt[(cs * 16 + l16) * 256];
      // phys chunk for logical chunk (quad+4k): 8*(k>>1) + ((quad+4*(k&1))^e)
      const ushort* bp0 = rowp + ((quad ^ e) * 8);          // k even base
      const ushort* bp1 = rowp + (((quad + 4) ^ e) * 8);    // k odd base
      floatx4 acc[4];
#pragma unroll
      for (int rb = 0; rb < 4; rb++) acc[rb] = (floatx4){0.f, 0.f, 0.f, 0.f};
#pragma unroll
      for (int m = 0; m < 4; m++) {
        short8 Bf0 = *(const short8*)(bp0 + m * 64);        // k = 2m
        short8 Bf1 = *(const short8*)(bp1 + m * 64);        // k = 2m+1
#pragma unroll
        for (int rb = 0; rb < 4; rb++)
          acc[rb] = __builtin_amdgcn_mfma_f32_16x16x32_bf16(Af[rb][2 * m], Bf0, acc[rb], 0, 0, 0);
#pragma unroll
        for (int rb = 0; rb < 4; rb++)
          acc[rb] = __builtin_amdgcn_mfma_f32_16x16x32_bf16(Af[rb][2 * m + 1], Bf1, acc[rb], 0, 0, 0);
      }
      float ca = 0.f;
#pragma unroll
      for (int rb = 0; rb < 4; rb++)
#pragma unroll
        for (int rr = 0; rr < 4; rr++) {
          float e2 = __builtin_amdgcn_exp2f(acc[rb][rr]);
          rsum[rb][rr] += e2;
          ca += e2;
        }
      if (!diag) {
        ca += __shfl_xor(ca, 16, 64);
        ca += __shfl_xor(ca, 32, 64);
        if (quad == 0)
          scol[w][ct * 64 + cs * 16 + l16] += ca;   // 16 lanes, 16 banks
      }
    }
  }

  // Row sums: reduce over the 16 column-lanes, atomics from l16==0 lanes.
#pragma unroll
  for (int rb = 0; rb < 4; rb++)
#pragma unroll
    for (int rr = 0; rr < 4; rr++) {
      float v = rsum[rb][rr];
#pragma unroll
      for (int off = 1; off < 16; off <<= 1) v += __shfl_xor(v, off, 64);
      if (l16 == 0)
        atomicAdd(&part[rowbase + rb * 16 + quad * 4 + rr], v);
    }

  if (!diag) {
    __syncthreads();
    float v = scol[0][tid] + scol[1][tid] + scol[2][tid] + scol[3][tid];
    atomicAdd(&part[cbase + tid], v);   // 256 coalesced lane-atomics
  }
}

// ---------------------------------------------------------------------------
// Wave-per-row loss term. 2048 blocks x 256 threads (4 rows/block).
//   neg_j = part[j] - exp2(selfdot_acc_j)    (matches the matmul diagonal)
//   t_j   = log(neg_j) - dp_acc_j * ln2      (dp_acc = 2*log2e*sim_pair)
// ---------------------------------------------------------------------------
__global__ __launch_bounds__(256) void k_rowterm(const ushort* __restrict__ zb,
                                                 const float* __restrict__ part,
                                                 float* __restrict__ bpart) {
  int j    = blockIdx.x * 4 + (threadIdx.x >> 6);
  int lane = threadIdx.x & 63;
  int pj   = (j + BATCH) & (NROW - 1);
  ushort4 ua = ((const ushort4*)(zb + (size_t)j  * DIM))[lane];
  ushort4 ub = ((const ushort4*)(zb + (size_t)pj * DIM))[lane];
  uint t;
  float ax, ay, az, aw, bx, by, bz, bw;
  t = (uint)ua.x << 16; ax = *(float*)&t;  t = (uint)ua.y << 16; ay = *(float*)&t;
  t = (uint)ua.z << 16; az = *(float*)&t;  t = (uint)ua.w << 16; aw = *(float*)&t;
  t = (uint)ub.x << 16; bx = *(float*)&t;  t = (uint)ub.y << 16; by = *(float*)&t;
  t = (uint)ub.z << 16; bz = *(float*)&t;  t = (uint)ub.w << 16; bw = *(float*)&t;
  float dp = ax * bx + ay * by + az * bz + aw * bw;
  float sd = ax * ax + ay * ay + az * az + aw * aw;
#pragma unroll
  for (int off = 1; off < 64; off <<= 1) {
    dp += __shfl_xor(dp, off, 64);
    sd += __shfl_xor(sd, off, 64);
  }
  __shared__ float sred[4];
  if (lane == 0) {
    float neg = part[j] - __builtin_amdgcn_exp2f(sd);
    sred[threadIdx.x >> 6] = logf(neg) - dp * LN2;
  }
  __syncthreads();
  if (threadIdx.x == 0)
    bpart[blockIdx.x] = sred[0] + sred[1] + sred[2] + sred[3];
}

__global__ void k_final(const float* __restrict__ bpart, float* __restrict__ out) {
  int t = threadIdx.x;  // 256 threads
  float v = 0.f;
#pragma unroll
  for (int i = 0; i < 8; i++) v += bpart[t + i * 256];
  int lane = t & 63;
#pragma unroll
  for (int off = 1; off < 64; off <<= 1) v += __shfl_xor(v, off, 64);
  __shared__ float sred[4];
  if (lane == 0) sred[t >> 6] = v;
  __syncthreads();
  if (t == 0) out[0] = (sred[0] + sred[1] + sred[2] + sred[3]) / (float)NROW;
}

extern "C" void kernel_launch(void* const* d_in, const int* in_sizes, int n_in,
                              void* d_out, int out_size, void* d_ws, size_t ws_size,
                              hipStream_t stream) {
  const float* z1 = (const float*)d_in[0];
  const float* z2 = (const float*)d_in[1];
  float* out = (float*)d_out;

  char* ws = (char*)d_ws;
  ushort* zb    = (ushort*)ws;                                   // 4 MiB
  float*  part  = (float*)(ws + (size_t)4 * 1024 * 1024);        // 32 KiB
  float*  bpart = (float*)(ws + (size_t)4 * 1024 * 1024 + 36864);

  k_prep<<<NROW / 4, 256, 0, stream>>>(z1, z2, zb, part);
  k_simsum<<<528, 256, 0, stream>>>(zb, part);
  k_rowterm<<<NROW / 4, 256, 0, stream>>>(zb, part, bpart);
  k_final<<<1, 256, 0, stream>>>(bpart, out);
}